// Round 1
// baseline (173.534 us; speedup 1.0000x reference)
//
#include <hip/hip_runtime.h>

// CINLayer: cin_out[b,f,d] = sum_{c,n} W[f,c,n] * xj[b,c,d] * x0[b,n,d]
//           cin_p_out[b,f] = sum_d cin_out[b,f,d]
// B=2048, C=64, N=64, D=64, F=128.
//
// Strategy: per c in 0..63:  acc2[(b,d),f] = sum_n x0[b,n,d]*W[f,c,n]  (bf16 MFMA)
//           acc[(b,d),f]   += xj[b,c,d] * acc2   (f32 VALU fold)
// A-operand (x0^T) is K-loop invariant -> hoisted to registers once.
// W pre-converted to bf16 in d_ws; W tile double-buffered in LDS, reg-prefetched.

typedef unsigned short u16;
typedef __attribute__((ext_vector_type(8))) short bf16x8;
typedef __attribute__((ext_vector_type(4))) short bf16x4;
typedef __attribute__((ext_vector_type(4))) float f32x4;

__device__ __forceinline__ u16 f2b(float f) {
  union { float f; unsigned u; } x; x.f = f;
  unsigned r = x.u + 0x7fffu + ((x.u >> 16) & 1u);   // RNE bf16 rounding
  return (u16)(r >> 16);
}
__device__ __forceinline__ float b2f_lo(unsigned u) {
  union { unsigned u; float f; } x; x.u = u << 16; return x.f;
}
__device__ __forceinline__ float b2f_hi(unsigned u) {
  union { unsigned u; float f; } x; x.u = u & 0xffff0000u; return x.f;
}
// 16B-chunk XOR swizzle within a 64-u16 row (bank-conflict-free b128 r/w)
__device__ __forceinline__ int swz(int row, int col) {
  return (col & 7) | ((((col >> 3) ^ row) & 7) << 3);
}

// ---- pre-pass: W f32 (F*C*N = 524288) -> bf16 in ws ----
__global__ __launch_bounds__(256) void wconv_kernel(const float* __restrict__ W,
                                                    u16* __restrict__ Wb) {
  int i = (blockIdx.x * 256 + threadIdx.x) * 8;
  const float4 a = *(const float4*)(W + i);
  const float4 b = *(const float4*)(W + i + 4);
  bf16x8 r;
  r[0] = (short)f2b(a.x); r[1] = (short)f2b(a.y);
  r[2] = (short)f2b(a.z); r[3] = (short)f2b(a.w);
  r[4] = (short)f2b(b.x); r[5] = (short)f2b(b.y);
  r[6] = (short)f2b(b.z); r[7] = (short)f2b(b.w);
  *(bf16x8*)(Wb + i) = r;
}

__global__ __launch_bounds__(256) void cin_kernel(
    const float* __restrict__ xj, const float* __restrict__ x0,
    const u16* __restrict__ Wb, float* __restrict__ out, float* __restrict__ pout) {
  extern __shared__ u16 smem[];
  u16* x0T = smem;          // [2][64][64]  x0T[bb*4096 + d*64 + swz(d,n)] = bf16(x0[b0+bb][n][d])
  u16* xjN = smem + 8192;   // [2][64][64]  xjN[bb*4096 + c*64 + d]       = bf16(xj[b0+bb][c][d])
  u16* Wt  = smem + 16384;  // [2][128][64] dbuf: Wt[buf*8192 + f*64 + swz(f,n)] = bf16(W[f][c][n])

  const int t  = threadIdx.x;
  const int b0 = blockIdx.x * 2;

  // ---- one-time: stage xj, x0 into LDS (x0 transposed) ----
  for (int bb = 0; bb < 2; ++bb) {
    const float* s0 = x0 + (size_t)(b0 + bb) * 4096;
    const float* sj = xj + (size_t)(b0 + bb) * 4096;
#pragma unroll
    for (int p = 0; p < 4; ++p) {
      const int e = p * 1024 + t * 4;
      const int r = e >> 6, d = e & 63;          // r = n (x0) or c (xj)
      const float4 v0 = *(const float4*)(s0 + e);
      const float4 vj = *(const float4*)(sj + e);
      x0T[bb * 4096 + (d + 0) * 64 + swz(d + 0, r)] = f2b(v0.x);
      x0T[bb * 4096 + (d + 1) * 64 + swz(d + 1, r)] = f2b(v0.y);
      x0T[bb * 4096 + (d + 2) * 64 + swz(d + 2, r)] = f2b(v0.z);
      x0T[bb * 4096 + (d + 3) * 64 + swz(d + 3, r)] = f2b(v0.w);
      bf16x4 jr;
      jr[0] = (short)f2b(vj.x); jr[1] = (short)f2b(vj.y);
      jr[2] = (short)f2b(vj.z); jr[3] = (short)f2b(vj.w);
      *(bf16x4*)&xjN[bb * 4096 + r * 64 + d] = jr;
    }
  }
  __syncthreads();

  const int wid = t >> 6, lane = t & 63;
  const int wr = wid >> 1, wc = wid & 1;        // wave row (m-half) / col (f-half)
  const int lr = lane & 15, lg = lane >> 4;

  // ---- hoisted A-fragments (x0 side), K-loop invariant ----
  // A[m][k=n] layout: lane holds A[m0+lr][kk*32 + lg*8 + i]
  bf16x8 af[4][2];
#pragma unroll
  for (int mf = 0; mf < 4; ++mf)
#pragma unroll
    for (int kk = 0; kk < 2; ++kk) {
      const int d = mf * 16 + lr;               // row within this wave's batch (bb = wr)
      af[mf][kk] = *(const bf16x8*)&x0T[wr * 4096 + d * 64 + swz(d, kk * 32 + lg * 8)];
    }

  f32x4 acc[4][4];
#pragma unroll
  for (int i = 0; i < 4; ++i)
#pragma unroll
    for (int j = 0; j < 4; ++j) acc[i][j] = (f32x4){0.f, 0.f, 0.f, 0.f};

  // ---- W prologue load (c = 0) ----
  bf16x8 wreg[4];
#pragma unroll
  for (int q = 0; q < 4; ++q) {
    const int e = q * 2048 + t * 8;
    wreg[q] = *(const bf16x8*)(Wb + (size_t)(e >> 6) * 4096 + (e & 63));
  }

  for (int c = 0; c < 64; ++c) {
    u16* wbuf = Wt + (c & 1) * 8192;
    // write current tile, prefetch next
#pragma unroll
    for (int q = 0; q < 4; ++q) {
      const int e = q * 2048 + t * 8;
      *(bf16x8*)&wbuf[(e >> 6) * 64 + swz(e >> 6, e & 63)] = wreg[q];
    }
    if (c < 63) {
#pragma unroll
      for (int q = 0; q < 4; ++q) {
        const int e = q * 2048 + t * 8;
        wreg[q] = *(const bf16x8*)(Wb + (size_t)(e >> 6) * 4096 + (c + 1) * 64 + (e & 63));
      }
    }
    __syncthreads();   // single barrier/iter: dbuf makes write(c+1) safe vs read(c)

    // B-fragments: B[k=n][col=f] = W[f][c][n]; lane holds Wtile[f0+lr][kk*32+lg*8+i]
    bf16x8 bfv[4][2];
#pragma unroll
    for (int nf = 0; nf < 4; ++nf)
#pragma unroll
      for (int kk = 0; kk < 2; ++kk) {
        const int row = wc * 64 + nf * 16 + lr;
        bfv[nf][kk] = *(const bf16x8*)&wbuf[row * 64 + swz(row, kk * 32 + lg * 8)];
      }

#pragma unroll
    for (int mf = 0; mf < 4; ++mf) {
      f32x4 z[4];
#pragma unroll
      for (int nf = 0; nf < 4; ++nf) {
        f32x4 zz = (f32x4){0.f, 0.f, 0.f, 0.f};
        zz = __builtin_amdgcn_mfma_f32_16x16x32_bf16(af[mf][0], bfv[nf][0], zz, 0, 0, 0);
        zz = __builtin_amdgcn_mfma_f32_16x16x32_bf16(af[mf][1], bfv[nf][1], zz, 0, 0, 0);
        z[nf] = zz;
      }
      // fold xj[b, c, d] into persistent accumulator (f32)
      const int d4 = mf * 16 + lg * 4;
      const bf16x4 xv = *(const bf16x4*)&xjN[wr * 4096 + c * 64 + d4];
      union { bf16x4 v; unsigned u[2]; } uu; uu.v = xv;
      const float xjf0 = b2f_lo(uu.u[0]), xjf1 = b2f_hi(uu.u[0]);
      const float xjf2 = b2f_lo(uu.u[1]), xjf3 = b2f_hi(uu.u[1]);
#pragma unroll
      for (int nf = 0; nf < 4; ++nf) {
        acc[mf][nf][0] += xjf0 * z[nf][0];
        acc[mf][nf][1] += xjf1 * z[nf][1];
        acc[mf][nf][2] += xjf2 * z[nf][2];
        acc[mf][nf][3] += xjf3 * z[nf][3];
      }
    }
  }

  // ---- epilogue: D frag layout col = lane&15 (f), row = (lane>>4)*4 + reg (d) ----
  const int b = b0 + wr;
  float psum[4] = {0.f, 0.f, 0.f, 0.f};
#pragma unroll
  for (int mf = 0; mf < 4; ++mf) {
    const int d = mf * 16 + lg * 4;
#pragma unroll
    for (int nf = 0; nf < 4; ++nf) {
      const int f = wc * 64 + nf * 16 + lr;
      const f32x4 v = acc[mf][nf];
      *(f32x4*)(out + (size_t)b * (128 * 64) + (size_t)f * 64 + d) = v;
      psum[nf] += v[0] + v[1] + v[2] + v[3];
    }
  }
#pragma unroll
  for (int nf = 0; nf < 4; ++nf) {
    float s = psum[nf];
    s += __shfl_xor(s, 16, 64);
    s += __shfl_xor(s, 32, 64);
    if (lg == 0) pout[(size_t)b * 128 + wc * 64 + nf * 16 + lr] = s;
  }
}

extern "C" void kernel_launch(void* const* d_in, const int* in_sizes, int n_in,
                              void* d_out, int out_size, void* d_ws, size_t ws_size,
                              hipStream_t stream) {
  const float* xj = (const float*)d_in[0];   // (2048, 64, 64)
  const float* x0 = (const float*)d_in[1];   // (2048, 64, 64)
  const float* W  = (const float*)d_in[2];   // (128, 64, 64)
  float* out  = (float*)d_out;               // cin_out (2048,128,64) then cin_p_out (2048,128)
  float* pout = out + (size_t)2048 * 128 * 64;
  u16* Wb = (u16*)d_ws;                      // 1 MiB bf16 copy of W

  wconv_kernel<<<256, 256, 0, stream>>>(W, Wb);
  cin_kernel<<<1024, 256, 65536, stream>>>(xj, x0, Wb, out, pout);
}